// Round 1
// baseline (239.626 us; speedup 1.0000x reference)
//
#include <hip/hip_runtime.h>
#include <math.h>

#define BB   512
#define NN   512
#define MM   128
#define CC   1024
#define ADDR 134
#define EPSF 1e-8f

__device__ __forceinline__ float softplus_f(float x) {
    return fmaxf(x, 0.0f) + log1pf(expf(-fabsf(x)));
}

__global__ __launch_bounds__(256) void ntm_head_kernel(
    const float* __restrict__ co,      // B x C
    const float* __restrict__ prev_w,  // B x N
    const float* __restrict__ mem,     // B x N x M
    const float* __restrict__ W_fc,    // C x ADDR
    const float* __restrict__ b_fc,    // ADDR
    float* __restrict__ out_rv,        // B x M
    float* __restrict__ out_w)         // B x N
{
    __shared__ __align__(16) float s_co[CC];
    __shared__ __align__(16) float s_k[MM];
    __shared__ float s_extra[8];
    __shared__ float s_bsim[NN];
    __shared__ float s_wg[NN];
    __shared__ float s_w[NN];
    __shared__ __align__(16) float s_part[8 * MM];
    __shared__ float s_red[8];
    __shared__ float s_params[8];

    const int t = threadIdx.x;
    const int b = blockIdx.x;

    // ---- phase 0: stage controller_out row ----
    for (int c = t; c < CC; c += 256) s_co[c] = co[(size_t)b * CC + c];
    __syncthreads();

    // ---- phase 1: fc (out = co @ W_fc + b_fc) ----
    if (t < ADDR) {
        float a0 = 0.f, a1 = 0.f, a2 = 0.f, a3 = 0.f;
        const float* Wp = W_fc + t;
        for (int c = 0; c < CC; c += 4) {
            float4 cv = *(const float4*)(s_co + c);
            a0 = fmaf(cv.x, Wp[(size_t)(c + 0) * ADDR], a0);
            a1 = fmaf(cv.y, Wp[(size_t)(c + 1) * ADDR], a1);
            a2 = fmaf(cv.z, Wp[(size_t)(c + 2) * ADDR], a2);
            a3 = fmaf(cv.w, Wp[(size_t)(c + 3) * ADDR], a3);
        }
        float r = ((a0 + a1) + (a2 + a3)) + b_fc[t];
        if (t < MM) s_k[t] = r; else s_extra[t - MM] = r;
    }
    __syncthreads();

    // ---- phase 1b: ||k|| + scalar params ----
    {
        float v = (t < MM) ? s_k[t] * s_k[t] : 0.0f;
        #pragma unroll
        for (int off = 32; off >= 1; off >>= 1) v += __shfl_xor(v, off, 64);
        if ((t & 63) == 0) s_red[t >> 6] = v;
        __syncthreads();
        if (t == 0) {
            float ks = s_red[0] + s_red[1] + s_red[2] + s_red[3];
            float norm_k = sqrtf(ks) + EPSF;
            float beta = softplus_f(s_extra[0]);
            float g = 1.0f / (1.0f + expf(-s_extra[1]));
            float e0 = s_extra[2], e1 = s_extra[3], e2 = s_extra[4];
            float mx = fmaxf(e0, fmaxf(e1, e2));
            float x0 = expf(e0 - mx), x1 = expf(e1 - mx), x2 = expf(e2 - mx);
            float inv = 1.0f / (x0 + x1 + x2);
            s_params[0] = beta / norm_k;
            s_params[1] = g;
            s_params[2] = x0 * inv;
            s_params[3] = x1 * inv;
            s_params[4] = x2 * inv;
            s_params[5] = 1.0f + softplus_f(s_extra[5]);
        }
    }
    __syncthreads();

    const float bnk = s_params[0];
    const float4* memb = (const float4*)(mem + (size_t)b * NN * MM);

    // ---- pass 1: beta * cosine similarity per row ----
    {
        const int gi = t >> 5;   // 8 groups of 32 lanes
        const int l  = t & 31;
        float4 kv = ((const float4*)s_k)[l];
        for (int n0 = gi; n0 < NN; n0 += 32) {
            float4 a0 = memb[(size_t)(n0     ) * 32 + l];
            float4 a1 = memb[(size_t)(n0 +  8) * 32 + l];
            float4 a2 = memb[(size_t)(n0 + 16) * 32 + l];
            float4 a3 = memb[(size_t)(n0 + 24) * 32 + l];
            float d0 = a0.x*kv.x + a0.y*kv.y + a0.z*kv.z + a0.w*kv.w;
            float q0 = a0.x*a0.x + a0.y*a0.y + a0.z*a0.z + a0.w*a0.w;
            float d1 = a1.x*kv.x + a1.y*kv.y + a1.z*kv.z + a1.w*kv.w;
            float q1 = a1.x*a1.x + a1.y*a1.y + a1.z*a1.z + a1.w*a1.w;
            float d2 = a2.x*kv.x + a2.y*kv.y + a2.z*kv.z + a2.w*kv.w;
            float q2 = a2.x*a2.x + a2.y*a2.y + a2.z*a2.z + a2.w*a2.w;
            float d3 = a3.x*kv.x + a3.y*kv.y + a3.z*kv.z + a3.w*kv.w;
            float q3 = a3.x*a3.x + a3.y*a3.y + a3.z*a3.z + a3.w*a3.w;
            #pragma unroll
            for (int off = 16; off >= 1; off >>= 1) {
                d0 += __shfl_xor(d0, off, 64); q0 += __shfl_xor(q0, off, 64);
                d1 += __shfl_xor(d1, off, 64); q1 += __shfl_xor(q1, off, 64);
                d2 += __shfl_xor(d2, off, 64); q2 += __shfl_xor(q2, off, 64);
                d3 += __shfl_xor(d3, off, 64); q3 += __shfl_xor(q3, off, 64);
            }
            if (l == 0) {
                s_bsim[n0     ] = bnk * d0 / (sqrtf(q0) + EPSF);
                s_bsim[n0 +  8] = bnk * d1 / (sqrtf(q1) + EPSF);
                s_bsim[n0 + 16] = bnk * d2 / (sqrtf(q2) + EPSF);
                s_bsim[n0 + 24] = bnk * d3 / (sqrtf(q3) + EPSF);
            }
        }
    }
    __syncthreads();

    // ---- softmax -> gate -> shift -> sharpen -> normalize ----
    {
        const int n1 = t, n2 = t + 256;
        float b1 = s_bsim[n1], b2 = s_bsim[n2];

        float m = fmaxf(b1, b2);
        #pragma unroll
        for (int off = 32; off >= 1; off >>= 1) m = fmaxf(m, __shfl_xor(m, off, 64));
        if ((t & 63) == 0) s_red[t >> 6] = m;
        __syncthreads();
        float M4 = fmaxf(fmaxf(s_red[0], s_red[1]), fmaxf(s_red[2], s_red[3]));
        __syncthreads();

        float e1 = expf(b1 - M4), e2 = expf(b2 - M4);
        float ls = e1 + e2;
        #pragma unroll
        for (int off = 32; off >= 1; off >>= 1) ls += __shfl_xor(ls, off, 64);
        if ((t & 63) == 0) s_red[t >> 6] = ls;
        __syncthreads();
        float S = s_red[0] + s_red[1] + s_red[2] + s_red[3];
        __syncthreads();

        const float invS = 1.0f / S;
        const float g = s_params[1];
        float wg1 = fmaf(g, e1 * invS, (1.0f - g) * prev_w[(size_t)b * NN + n1]);
        float wg2 = fmaf(g, e2 * invS, (1.0f - g) * prev_w[(size_t)b * NN + n2]);
        s_wg[n1] = wg1;
        s_wg[n2] = wg2;
        __syncthreads();

        const float sh0 = s_params[2], sh1 = s_params[3], sh2 = s_params[4];
        const float gamma = s_params[5];
        float ws1 = sh0 * s_wg[(n1 + NN - 1) & (NN - 1)] + sh1 * wg1 + sh2 * s_wg[(n1 + 1) & (NN - 1)];
        float ws2 = sh0 * s_wg[(n2 + NN - 1) & (NN - 1)] + sh1 * wg2 + sh2 * s_wg[(n2 + 1) & (NN - 1)];
        float wp1 = powf(ws1, gamma);
        float wp2 = powf(ws2, gamma);

        float lz = wp1 + wp2;
        #pragma unroll
        for (int off = 32; off >= 1; off >>= 1) lz += __shfl_xor(lz, off, 64);
        if ((t & 63) == 0) s_red[t >> 6] = lz;
        __syncthreads();
        float Z = s_red[0] + s_red[1] + s_red[2] + s_red[3];
        __syncthreads();

        const float invZ = 1.0f / (Z + EPSF);
        float w1 = wp1 * invZ, w2 = wp2 * invZ;
        s_w[n1] = w1;
        s_w[n2] = w2;
        out_w[(size_t)b * NN + n1] = w1;
        out_w[(size_t)b * NN + n2] = w2;
    }
    __syncthreads();

    // ---- pass 2: read_vec = w @ mem ----
    {
        const int q = t >> 5;    // 8 groups, 64 rows each
        const int l = t & 31;    // float4 column
        float4 acc = make_float4(0.f, 0.f, 0.f, 0.f);
        const int nb = q * 64;
        for (int n = nb; n < nb + 64; n += 4) {
            float4 a0 = memb[(size_t)(n    ) * 32 + l];
            float4 a1 = memb[(size_t)(n + 1) * 32 + l];
            float4 a2 = memb[(size_t)(n + 2) * 32 + l];
            float4 a3 = memb[(size_t)(n + 3) * 32 + l];
            float w0 = s_w[n], w1 = s_w[n + 1], w2 = s_w[n + 2], w3 = s_w[n + 3];
            acc.x = fmaf(w0, a0.x, acc.x); acc.y = fmaf(w0, a0.y, acc.y);
            acc.z = fmaf(w0, a0.z, acc.z); acc.w = fmaf(w0, a0.w, acc.w);
            acc.x = fmaf(w1, a1.x, acc.x); acc.y = fmaf(w1, a1.y, acc.y);
            acc.z = fmaf(w1, a1.z, acc.z); acc.w = fmaf(w1, a1.w, acc.w);
            acc.x = fmaf(w2, a2.x, acc.x); acc.y = fmaf(w2, a2.y, acc.y);
            acc.z = fmaf(w2, a2.z, acc.z); acc.w = fmaf(w2, a2.w, acc.w);
            acc.x = fmaf(w3, a3.x, acc.x); acc.y = fmaf(w3, a3.y, acc.y);
            acc.z = fmaf(w3, a3.z, acc.z); acc.w = fmaf(w3, a3.w, acc.w);
        }
        *((float4*)&s_part[q * MM + l * 4]) = acc;
        __syncthreads();
        if (t < MM) {
            float r = 0.f;
            #pragma unroll
            for (int q2 = 0; q2 < 8; ++q2) r += s_part[q2 * MM + t];
            out_rv[(size_t)b * MM + t] = r;
        }
    }
}

extern "C" void kernel_launch(void* const* d_in, const int* in_sizes, int n_in,
                              void* d_out, int out_size, void* d_ws, size_t ws_size,
                              hipStream_t stream) {
    const float* co     = (const float*)d_in[0];
    const float* prev_w = (const float*)d_in[1];
    const float* mem    = (const float*)d_in[2];
    const float* W_fc   = (const float*)d_in[3];
    const float* b_fc   = (const float*)d_in[4];
    float* out = (float*)d_out;
    ntm_head_kernel<<<BB, 256, 0, stream>>>(co, prev_w, mem, W_fc, b_fc,
                                            out, out + (size_t)BB * MM);
}